// Round 2
// baseline (158.745 us; speedup 1.0000x reference)
//
#include <hip/hip_runtime.h>

typedef unsigned short u16;
typedef unsigned int u32;
typedef __bf16 bf16x8 __attribute__((ext_vector_type(8)));
typedef float f32x4 __attribute__((ext_vector_type(4)));
typedef unsigned short u16x4 __attribute__((ext_vector_type(4)));

#define LOG2E 1.4426950408889634f

#if __has_builtin(__builtin_amdgcn_exp2f)
#define EXP2F(x) __builtin_amdgcn_exp2f(x)
#else
#define EXP2F(x) exp2f(x)
#endif

__device__ __forceinline__ u16 f2bf(float f) {
    union { float f; u32 u; } a; a.f = f;
    u32 u = a.u;
    u += 0x7FFFu + ((u >> 16) & 1u);   // RNE (finite inputs)
    return (u16)(u >> 16);
}
__device__ __forceinline__ bf16x8 ldg8(const u16* p) {
    return *reinterpret_cast<const bf16x8*>(p);
}
// pack two fp32 -> two bf16 in one instruction where available
#if __has_builtin(__builtin_amdgcn_cvt_pk_bf16_f32)
__device__ __forceinline__ u32 pack2(float a, float b) {
    auto r = __builtin_amdgcn_cvt_pk_bf16_f32(a, b);   // v_cvt_pk_bf16_f32
    return __builtin_bit_cast(u32, r);
}
#else
__device__ __forceinline__ u32 pack2(float a, float b) {
    u32 ua = __float_as_uint(a) + 0x8000u;
    u32 ub = __float_as_uint(b) + 0x8000u;
    return __builtin_amdgcn_perm(ub, ua, 0x07060302);
}
#endif
// async global -> LDS, 16 B per lane. LDS dest = wave-uniform base + lane*16.
__device__ __forceinline__ void async16(const void* g, void* l) {
    __builtin_amdgcn_global_load_lds(
        (const __attribute__((address_space(1))) u32*)g,
        (__attribute__((address_space(3))) u32*)l, 16, 0, 0);
}

#define MFMA16(a, b, c) __builtin_amdgcn_mfma_f32_16x16x32_bf16((a), (b), (c), 0, 0, 0)

// ---------------------------------------------------------------------------
// Fused prep: y<8 -> transpose X tile; y in 8..11 -> pack weight matrix;
// y==12 -> lqw * log2(e) into global fp32 (4 blocks). Grid (64, 13).
// ---------------------------------------------------------------------------
__global__ __launch_bounds__(256) void prep(const float* __restrict__ X,
                                            u16* __restrict__ Xt,
                                            const float* __restrict__ s0,
                                            const float* __restrict__ s1,
                                            const float* __restrict__ s2,
                                            const float* __restrict__ s3,
                                            u16* __restrict__ Wqkv,
                                            u16* __restrict__ Wp,
                                            const float* __restrict__ lqw,
                                            float* __restrict__ lqw2g) {
    __shared__ u16 tile[64][65];
    const int tid = threadIdx.x;
    const int y = blockIdx.y;

    if (y < 8) {                                  // transpose 64x64 tile
        const int t0 = blockIdx.x * 64;
        const int c0 = y * 64;
#pragma unroll
        for (int i = 0; i < 16; ++i) {
            int idx = tid + i * 256;
            int r = idx >> 6, cc = idx & 63;
            tile[r][cc] = f2bf(X[(size_t)(c0 + r) * 4096 + t0 + cc]);
        }
        __syncthreads();
#pragma unroll
        for (int i = 0; i < 16; ++i) {
            int idx = tid + i * 256;
            int tr = idx >> 6, cc = idx & 63;
            Xt[(size_t)(t0 + tr) * 512 + c0 + cc] = tile[cc][tr];
        }
    } else if (y < 12) {                          // pack one 512x512 weight
        const int m = y - 8;
        const float* s = (m == 0) ? s0 : (m == 1) ? s1 : (m == 2) ? s2 : s3;
        u16* d = (m == 3) ? Wp : Wqkv + (size_t)m * 262144;
#pragma unroll
        for (int j = 0; j < 4; ++j) {
            int i = blockIdx.x * 1024 + j * 256 + tid;
            float4 v = reinterpret_cast<const float4*>(s)[i];
            u16x4 o;
            o[0] = f2bf(v.x); o[1] = f2bf(v.y); o[2] = f2bf(v.z); o[3] = f2bf(v.w);
            reinterpret_cast<u16x4*>(d)[i] = o;
        }
    } else {                                      // lqw * LOG2E (1024 float4)
        if (blockIdx.x < 4) {
            int i = blockIdx.x * 256 + tid;
            float4 v = reinterpret_cast<const float4*>(lqw)[i];
            v.x *= LOG2E; v.y *= LOG2E; v.z *= LOG2E; v.w *= LOG2E;
            reinterpret_cast<float4*>(lqw2g)[i] = v;
        }
    }
}

// ---------------------------------------------------------------------------
// Fused QKV GEMM, LDS-staged. Swizzle on (row>>1)&3: fragment ds_read_b128
// 2-way (free) instead of 4-way.
// ---------------------------------------------------------------------------
__global__ __launch_bounds__(512, 2) void qkv_gemm(const u16* __restrict__ Wqkv,
                                                   const u16* __restrict__ Xt,
                                                   const float* __restrict__ qb,
                                                   const float* __restrict__ kb,
                                                   const float* __restrict__ vb,
                                                   u16* __restrict__ Qt,
                                                   u16* __restrict__ Kt,
                                                   u16* __restrict__ Vp) {
    __shared__ __align__(16) u16 Al[2][128 * 32];
    __shared__ __align__(16) u16 Bl[2][128 * 32];

    const int tid = threadIdx.x;
    const int w = tid >> 6, lane = tid & 63;
    const int quad = lane >> 4, lm = lane & 15;
    const int wm = w & 1, wn = w >> 1;
    const int n0 = blockIdx.x * 128;
    const int my = blockIdx.y;
    const int m0 = my * 128;

    const int arow = lane >> 2;
    const int sch = (lane & 3) ^ ((lane >> 3) & 3);   // source chunk (XOR on row>>1)
    const u16* agp = Wqkv + (size_t)(m0 + w * 16 + arow) * 512 + sch * 8;
    const u16* bgp = Xt + (size_t)(n0 + w * 16 + arow) * 512 + sch * 8;

    async16(agp, &Al[0][w * 16 * 32]);
    async16(bgp, &Bl[0][w * 16 * 32]);
    agp += 32; bgp += 32;

    const int FOFF = lm * 64 + ((quad ^ ((lm >> 1) & 3)) << 4);

    f32x4 acc[4][2];
#pragma unroll
    for (int mt = 0; mt < 4; ++mt)
#pragma unroll
        for (int bt = 0; bt < 2; ++bt) acc[mt][bt] = (f32x4){0.f, 0.f, 0.f, 0.f};

    __syncthreads();

    for (int s = 0; s < 16; ++s) {
        const int buf = s & 1;
        if (s < 15) {
            async16(agp, &Al[buf ^ 1][w * 16 * 32]);
            async16(bgp, &Bl[buf ^ 1][w * 16 * 32]);
            agp += 32; bgp += 32;
        }
        const char* Ab = (const char*)&Al[buf][0];
        const char* Bb = (const char*)&Bl[buf][0];
        bf16x8 af[4], bfr[2];
#pragma unroll
        for (int mt = 0; mt < 4; ++mt)
            af[mt] = *(const bf16x8*)(Ab + wm * 4096 + mt * 1024 + FOFF);
#pragma unroll
        for (int bt = 0; bt < 2; ++bt)
            bfr[bt] = *(const bf16x8*)(Bb + wn * 2048 + bt * 1024 + FOFF);
#pragma unroll
        for (int mt = 0; mt < 4; ++mt)
#pragma unroll
            for (int bt = 0; bt < 2; ++bt)
                acc[mt][bt] = MFMA16(af[mt], bfr[bt], acc[mt][bt]);
        __syncthreads();
    }

    const int mat = my >> 2;                     // 0=Q, 1=K, 2=V
    const float* bias = (mat == 0) ? qb : (mat == 1) ? kb : vb;
    const int chbase = (my & 3) * 128 + wm * 64 + quad * 4;

    if (mat < 2) {
        u16* out = mat ? Kt : Qt;
        const float sc = mat ? 1.0f : 0.125f * LOG2E;
#pragma unroll
        for (int mt = 0; mt < 4; ++mt) {
            const int ch = chbase + mt * 16;
            float4 bv = *(const float4*)(bias + ch);
            float bvf[4] = {bv.x, bv.y, bv.z, bv.w};
#pragma unroll
            for (int bt = 0; bt < 2; ++bt) {
                int tok = n0 + wn * 32 + bt * 16 + lm;
                u16x4 pk;
#pragma unroll
                for (int r = 0; r < 4; ++r)
                    pk[r] = f2bf((acc[mt][bt][r] + bvf[r]) * sc);
                *(u16x4*)(out + (size_t)tok * 512 + ch) = pk;
            }
        }
    } else {
#pragma unroll
        for (int mt = 0; mt < 4; ++mt) {
            const int ch = chbase + mt * 16;
            float4 bv = *(const float4*)(bias + ch);
            float bvf[4] = {bv.x, bv.y, bv.z, bv.w};
#pragma unroll
            for (int bt = 0; bt < 2; ++bt) {
                int g = bt * 16 + lm;
                int col = n0 + wn * 32 + 8 * ((g >> 2) & 3) + 4 * ((g >> 4) & 1) + (g & 3);
#pragma unroll
                for (int r = 0; r < 4; ++r)
                    Vp[(size_t)(ch + r) * 4096 + col] = f2bf(acc[mt][bt][r] + bvf[r]);
            }
        }
    }
}

// ---------------------------------------------------------------------------
// Output projection, LDS-staged (same 2-way swizzle fix).
// ---------------------------------------------------------------------------
__global__ __launch_bounds__(256, 2) void out_gemm(const u16* __restrict__ Wp,
                                                   const u16* __restrict__ Ot,
                                                   const float* __restrict__ pb,
                                                   float* __restrict__ out) {
    __shared__ __align__(16) u16 Al[2][128 * 32];
    __shared__ __align__(16) u16 Bl[2][64 * 32];

    const int tid = threadIdx.x;
    const int w = tid >> 6, lane = tid & 63;
    const int quad = lane >> 4, lm = lane & 15;
    const int wm = w & 1, wn = w >> 1;
    const int n0 = blockIdx.x * 64;
    const int m0 = blockIdx.y * 128;

    const int arow = lane >> 2;
    const int sch = (lane & 3) ^ ((lane >> 3) & 3);
    const u16* agp0 = Wp + (size_t)(m0 + w * 16 + arow) * 512 + sch * 8;
    const u16* agp1 = agp0 + (size_t)64 * 512;
    const u16* bgp = Ot + (size_t)(n0 + w * 16 + arow) * 512 + sch * 8;

    async16(agp0, &Al[0][w * 16 * 32]);
    async16(agp1, &Al[0][(64 + w * 16) * 32]);
    async16(bgp, &Bl[0][w * 16 * 32]);
    agp0 += 32; agp1 += 32; bgp += 32;

    const int FOFF = lm * 64 + ((quad ^ ((lm >> 1) & 3)) << 4);

    f32x4 acc[4][2];
#pragma unroll
    for (int mt = 0; mt < 4; ++mt)
#pragma unroll
        for (int bt = 0; bt < 2; ++bt) acc[mt][bt] = (f32x4){0.f, 0.f, 0.f, 0.f};

    __syncthreads();

    for (int s = 0; s < 16; ++s) {
        const int buf = s & 1;
        if (s < 15) {
            async16(agp0, &Al[buf ^ 1][w * 16 * 32]);
            async16(agp1, &Al[buf ^ 1][(64 + w * 16) * 32]);
            async16(bgp, &Bl[buf ^ 1][w * 16 * 32]);
            agp0 += 32; agp1 += 32; bgp += 32;
        }
        const char* Ab = (const char*)&Al[buf][0];
        const char* Bb = (const char*)&Bl[buf][0];
        bf16x8 af[4], bfr[2];
#pragma unroll
        for (int mt = 0; mt < 4; ++mt)
            af[mt] = *(const bf16x8*)(Ab + wm * 4096 + mt * 1024 + FOFF);
#pragma unroll
        for (int bt = 0; bt < 2; ++bt)
            bfr[bt] = *(const bf16x8*)(Bb + wn * 2048 + bt * 1024 + FOFF);
#pragma unroll
        for (int mt = 0; mt < 4; ++mt)
#pragma unroll
            for (int bt = 0; bt < 2; ++bt)
                acc[mt][bt] = MFMA16(af[mt], bfr[bt], acc[mt][bt]);
        __syncthreads();
    }

#pragma unroll
    for (int mt = 0; mt < 4; ++mt) {
        const int ch = m0 + wm * 64 + mt * 16 + quad * 4;
        float4 bv = *(const float4*)(pb + ch);
        float bvf[4] = {bv.x, bv.y, bv.z, bv.w};
#pragma unroll
        for (int bt = 0; bt < 2; ++bt) {
            int tok = n0 + wn * 32 + bt * 16 + lm;
#pragma unroll
            for (int r = 0; r < 4; ++r)
                out[(size_t)(ch + r) * 4096 + tok] = acc[mt][bt][r] + bvf[r];
        }
    }
}

// ---------------------------------------------------------------------------
// Flash attention, max-free softmax, in-block split-K=4, 32 queries/wave —
// ZERO LDS STAGING. Round-1 post-mortem: with q-reuse=2, every staged LDS
// byte is read exactly once (K reads/step = K tile size), so LDS staging is
// a pure pass-through costing a per-step __syncthreads + vmcnt(0) drain.
// All pipes were <35% busy -> latency/barrier-bound, not throughput-bound.
// Fix: load K/V MFMA fragments DIRECTLY from global (L2-resident: K+V = 8 MB,
// FETCH_SIZE only 35 MB). Kt row-major gives K frags at
// Kt[(key+lm)*512 + hq + quad*8]; Vp's column permutation (built for
// contiguous 16B chunks) delivers keys in exactly the PV k-slot order
// (j>>2)*16 + quad*4 + (j&3), so V frags are Vp[(hq+d)*4096 + kt0 + quad*8].
// Per lane 16 B, quads contiguous -> 16x64B requests/instr. No in-loop
// barriers at all; waves run free for 32 steps; one barrier at split-K merge.
// LDS = 49 KB merge buffer only (XOR-swizzled slots: old linear layout was a
// 16-way conflict -> the 2.06M SQ_LDS_BANK_CONFLICT).
// ---------------------------------------------------------------------------
__global__ __launch_bounds__(512, 4) void flash_attn(const u16* __restrict__ Qt,
                                                     const u16* __restrict__ Kt,
                                                     const u16* __restrict__ Vp,
                                                     const float* __restrict__ lqw2g,
                                                     u16* __restrict__ Ot) {
    __shared__ __align__(16) float mbuf[6 * 2048 + 192];   // 48.75 KB, merge only

    const int tid = threadIdx.x;
    const int w = tid >> 6, lane = tid & 63;         // w = 0..7
    const int quad = lane >> 4, lm = lane & 15;
    const int qg = w & 1, quarter = w >> 1;
    const int h = blockIdx.y, hq = h * 64;
    const int q0 = blockIdx.x * 64 + qg * 32;
    const int kstart = quarter * 1024;

    // Q fragments (2 subtiles x d0/d1)
    const u16* qbase = Qt + (size_t)(q0 + lm) * 512 + hq + quad * 8;
    const bf16x8 bq0a = ldg8(qbase);
    const bf16x8 bq1a = ldg8(qbase + 32);
    const bf16x8 bq0b = ldg8(qbase + 16 * 512);
    const bf16x8 bq1b = ldg8(qbase + 16 * 512 + 32);

    // direct-global fragment bases
    const u16* kfp = Kt + (size_t)(kstart + lm) * 512 + hq + quad * 8;   // + key*512
    const u16* vfp = Vp + (size_t)(hq + lm) * 4096 + kstart + quad * 8;  // + d*4096 + key

    union { u32 u[4]; bf16x8 v; } onesu;
    onesu.u[0] = onesu.u[1] = onesu.u[2] = onesu.u[3] = 0x3F803F80u;
    const bf16x8 onesv = onesu.v;

    f32x4 acc_o[4][2];
#pragma unroll
    for (int mt = 0; mt < 4; ++mt) {
        acc_o[mt][0] = (f32x4){0.f, 0.f, 0.f, 0.f};
        acc_o[mt][1] = (f32x4){0.f, 0.f, 0.f, 0.f};
    }
    f32x4 acc_l[2];
    acc_l[0] = (f32x4){0.f, 0.f, 0.f, 0.f};
    acc_l[1] = (f32x4){0.f, 0.f, 0.f, 0.f};

#pragma unroll 2
    for (int t = 0; t < 32; ++t) {
        const int kt0 = kstart + t * 32;
        // --- QK^T for 32 keys (2 x 16-key groups), bias as C-init ---
        u32 pk[2][2][2];
#pragma unroll
        for (int nt = 0; nt < 2; ++nt) {
            const u16* kp = kfp + (size_t)(t * 32 + nt * 16) * 512;
            bf16x8 k0 = ldg8(kp);         // d 0..31
            bf16x8 k1 = ldg8(kp + 32);    // d 32..63
            f32x4 bias = *(const f32x4*)(lqw2g + kt0 + nt * 16 + quad * 4);
            f32x4 a0 = MFMA16(k0, bq0a, bias);
            a0 = MFMA16(k1, bq1a, a0);
            f32x4 a1 = MFMA16(k0, bq0b, bias);
            a1 = MFMA16(k1, bq1b, a1);
            pk[nt][0][0] = pack2(EXP2F(a0[0]), EXP2F(a0[1]));
            pk[nt][0][1] = pack2(EXP2F(a0[2]), EXP2F(a0[3]));
            pk[nt][1][0] = pack2(EXP2F(a1[0]), EXP2F(a1[1]));
            pk[nt][1][1] = pack2(EXP2F(a1[2]), EXP2F(a1[3]));
        }
        union { u32 u[4]; bf16x8 v; } bb0, bb1;
        bb0.u[0] = pk[0][0][0]; bb0.u[1] = pk[0][0][1];
        bb0.u[2] = pk[1][0][0]; bb0.u[3] = pk[1][0][1];
        bb1.u[0] = pk[0][1][0]; bb1.u[1] = pk[0][1][1];
        bb1.u[2] = pk[1][1][0]; bb1.u[3] = pk[1][1][1];
        // --- PV + row-sum (ones row) ---
#pragma unroll
        for (int mt = 0; mt < 4; ++mt) {
            bf16x8 vv = ldg8(vfp + (size_t)(mt * 16) * 4096 + t * 32);
            acc_o[mt][0] = MFMA16(vv, bb0.v, acc_o[mt][0]);
            acc_o[mt][1] = MFMA16(vv, bb1.v, acc_o[mt][1]);
        }
        acc_l[0] = MFMA16(onesv, bb0.v, acc_l[0]);
        acc_l[1] = MFMA16(onesv, bb1.v, acc_l[1]);
    }

    // ---- split-K merge: pure add (max-free softmax), 4-way ----
    // slot-swizzled layout: row r (0..31), 16B slot sl = (mt*4+quad) ^ (r&15)
    if (quarter != 0) {
        const int widx = (quarter - 1) * 2 + qg;     // 0..5
        float* ob = mbuf + widx * 2048;              // 32 q x 64 d fp32
#pragma unroll
        for (int s = 0; s < 2; ++s) {
            const int r = s * 16 + lm;
#pragma unroll
            for (int mt = 0; mt < 4; ++mt) {
                const int sl = (mt * 4 + quad) ^ (r & 15);
                *(f32x4*)(ob + r * 64 + sl * 4) = acc_o[mt][s];
            }
        }
        if (quad == 0) {
            mbuf[12288 + widx * 32 + lm] = acc_l[0][0];
            mbuf[12288 + widx * 32 + 16 + lm] = acc_l[1][0];
        }
    }
    __syncthreads();
    if (quarter != 0) return;

#pragma unroll
    for (int s = 0; s < 2; ++s) {
        const int r = s * 16 + lm;
        float lsum = acc_l[s][0];
#pragma unroll
        for (int p = 0; p < 3; ++p)
            lsum += mbuf[12288 + (p * 2 + qg) * 32 + s * 16 + lm];
        const float inv = 1.0f / lsum;
#pragma unroll
        for (int mt = 0; mt < 4; ++mt) {
            const int sl = (mt * 4 + quad) ^ (r & 15);
            f32x4 o = acc_o[mt][s];
#pragma unroll
            for (int p = 0; p < 3; ++p)
                o += *(const f32x4*)(mbuf + (p * 2 + qg) * 2048 + r * 64 + sl * 4);
            u16x4 pkv;
#pragma unroll
            for (int r2 = 0; r2 < 4; ++r2)
                pkv[r2] = f2bf(o[r2] * inv);
            *reinterpret_cast<u16x4*>(Ot + (size_t)(q0 + s * 16 + lm) * 512 +
                                      hq + mt * 16 + quad * 4) = pkv;
        }
    }
}

// ---------------------------------------------------------------------------
extern "C" void kernel_launch(void* const* d_in, const int* in_sizes, int n_in,
                              void* d_out, int out_size, void* d_ws, size_t ws_size,
                              hipStream_t stream) {
    (void)in_sizes; (void)n_in; (void)out_size; (void)ws_size;
    const float* X   = (const float*)d_in[0];
    const float* qw  = (const float*)d_in[1];
    const float* qb  = (const float*)d_in[2];
    const float* kw  = (const float*)d_in[3];
    const float* kb  = (const float*)d_in[4];
    const float* vw  = (const float*)d_in[5];
    const float* vb  = (const float*)d_in[6];
    const float* pw  = (const float*)d_in[7];
    const float* pb  = (const float*)d_in[8];
    const float* lqw = (const float*)d_in[9];

    const size_t E = (size_t)4096 * 512;
    const size_t WE = (size_t)512 * 512;
    u16* Xt    = (u16*)d_ws;
    u16* Qt    = Xt + E;
    u16* Kt    = Qt + E;
    u16* Vp    = Kt + E;
    u16* Wqkv  = Vp + E;          // 1536 x 512 stacked
    u16* Wp    = Wqkv + 3 * WE;
    float* lqw2g = (float*)(Wp + WE);   // 4096 fp32, 16B-aligned
    u16* Ot    = Xt;              // reuse (dead after qkv)

    prep<<<dim3(64, 13), dim3(256), 0, stream>>>(X, Xt, qw, kw, vw, pw,
                                                 Wqkv, Wp, lqw, lqw2g);
    qkv_gemm<<<dim3(32, 12), dim3(512), 0, stream>>>(Wqkv, Xt, qb, kb, vb, Qt, Kt, Vp);
    flash_attn<<<dim3(64, 8), dim3(512), 0, stream>>>(Qt, Kt, Vp, lqw2g, Ot);
    out_gemm<<<dim3(64, 4), dim3(256), 0, stream>>>(Wp, Ot, pb, (float*)d_out);
}

// Round 3
// 78.428 us; speedup vs baseline: 2.0241x; 2.0241x over previous
//
#include <hip/hip_runtime.h>

typedef unsigned short u16;
typedef unsigned int u32;
typedef __bf16 bf16x8 __attribute__((ext_vector_type(8)));
typedef float f32x4 __attribute__((ext_vector_type(4)));
typedef unsigned short u16x4 __attribute__((ext_vector_type(4)));

#define LOG2E 1.4426950408889634f

#if __has_builtin(__builtin_amdgcn_exp2f)
#define EXP2F(x) __builtin_amdgcn_exp2f(x)
#else
#define EXP2F(x) exp2f(x)
#endif

__device__ __forceinline__ u16 f2bf(float f) {
    union { float f; u32 u; } a; a.f = f;
    u32 u = a.u;
    u += 0x7FFFu + ((u >> 16) & 1u);   // RNE (finite inputs)
    return (u16)(u >> 16);
}
__device__ __forceinline__ bf16x8 ldg8(const u16* p) {
    return *reinterpret_cast<const bf16x8*>(p);
}
#if __has_builtin(__builtin_amdgcn_cvt_pk_bf16_f32)
__device__ __forceinline__ u32 pack2(float a, float b) {
    auto r = __builtin_amdgcn_cvt_pk_bf16_f32(a, b);   // v_cvt_pk_bf16_f32
    return __builtin_bit_cast(u32, r);
}
#else
__device__ __forceinline__ u32 pack2(float a, float b) {
    u32 ua = __float_as_uint(a) + 0x8000u;
    u32 ub = __float_as_uint(b) + 0x8000u;
    return __builtin_amdgcn_perm(ub, ua, 0x07060302);
}
#endif
// async global -> LDS, 16 B per lane. LDS dest = wave-uniform base + lane*16.
__device__ __forceinline__ void async16(const void* g, void* l) {
    __builtin_amdgcn_global_load_lds(
        (const __attribute__((address_space(1))) u32*)g,
        (__attribute__((address_space(3))) u32*)l, 16, 0, 0);
}

#define MFMA16(a, b, c) __builtin_amdgcn_mfma_f32_16x16x32_bf16((a), (b), (c), 0, 0, 0)

// ---------------------------------------------------------------------------
// Fused prep: y<8 -> transpose X tile; y in 8..11 -> pack weight matrix;
// y==12 -> lqw * log2(e) into global fp32 (4 blocks). Grid (64, 13).
// ---------------------------------------------------------------------------
__global__ __launch_bounds__(256) void prep(const float* __restrict__ X,
                                            u16* __restrict__ Xt,
                                            const float* __restrict__ s0,
                                            const float* __restrict__ s1,
                                            const float* __restrict__ s2,
                                            const float* __restrict__ s3,
                                            u16* __restrict__ Wqkv,
                                            u16* __restrict__ Wp,
                                            const float* __restrict__ lqw,
                                            float* __restrict__ lqw2g) {
    __shared__ u16 tile[64][65];
    const int tid = threadIdx.x;
    const int y = blockIdx.y;

    if (y < 8) {                                  // transpose 64x64 tile
        const int t0 = blockIdx.x * 64;
        const int c0 = y * 64;
#pragma unroll
        for (int i = 0; i < 16; ++i) {
            int idx = tid + i * 256;
            int r = idx >> 6, cc = idx & 63;
            tile[r][cc] = f2bf(X[(size_t)(c0 + r) * 4096 + t0 + cc]);
        }
        __syncthreads();
#pragma unroll
        for (int i = 0; i < 16; ++i) {
            int idx = tid + i * 256;
            int tr = idx >> 6, cc = idx & 63;
            Xt[(size_t)(t0 + tr) * 512 + c0 + cc] = tile[cc][tr];
        }
    } else if (y < 12) {                          // pack one 512x512 weight
        const int m = y - 8;
        const float* s = (m == 0) ? s0 : (m == 1) ? s1 : (m == 2) ? s2 : s3;
        u16* d = (m == 3) ? Wp : Wqkv + (size_t)m * 262144;
#pragma unroll
        for (int j = 0; j < 4; ++j) {
            int i = blockIdx.x * 1024 + j * 256 + tid;
            float4 v = reinterpret_cast<const float4*>(s)[i];
            u16x4 o;
            o[0] = f2bf(v.x); o[1] = f2bf(v.y); o[2] = f2bf(v.z); o[3] = f2bf(v.w);
            reinterpret_cast<u16x4*>(d)[i] = o;
        }
    } else {                                      // lqw * LOG2E (1024 float4)
        if (blockIdx.x < 4) {
            int i = blockIdx.x * 256 + tid;
            float4 v = reinterpret_cast<const float4*>(lqw)[i];
            v.x *= LOG2E; v.y *= LOG2E; v.z *= LOG2E; v.w *= LOG2E;
            reinterpret_cast<float4*>(lqw2g)[i] = v;
        }
    }
}

// ---------------------------------------------------------------------------
// Fused QKV GEMM, LDS-staged (unchanged, known-good).
// ---------------------------------------------------------------------------
__global__ __launch_bounds__(512, 2) void qkv_gemm(const u16* __restrict__ Wqkv,
                                                   const u16* __restrict__ Xt,
                                                   const float* __restrict__ qb,
                                                   const float* __restrict__ kb,
                                                   const float* __restrict__ vb,
                                                   u16* __restrict__ Qt,
                                                   u16* __restrict__ Kt,
                                                   u16* __restrict__ Vp) {
    __shared__ __align__(16) u16 Al[2][128 * 32];
    __shared__ __align__(16) u16 Bl[2][128 * 32];

    const int tid = threadIdx.x;
    const int w = tid >> 6, lane = tid & 63;
    const int quad = lane >> 4, lm = lane & 15;
    const int wm = w & 1, wn = w >> 1;
    const int n0 = blockIdx.x * 128;
    const int my = blockIdx.y;
    const int m0 = my * 128;

    const int arow = lane >> 2;
    const int sch = (lane & 3) ^ ((lane >> 3) & 3);   // source chunk (XOR on row>>1)
    const u16* agp = Wqkv + (size_t)(m0 + w * 16 + arow) * 512 + sch * 8;
    const u16* bgp = Xt + (size_t)(n0 + w * 16 + arow) * 512 + sch * 8;

    async16(agp, &Al[0][w * 16 * 32]);
    async16(bgp, &Bl[0][w * 16 * 32]);
    agp += 32; bgp += 32;

    const int FOFF = lm * 64 + ((quad ^ ((lm >> 1) & 3)) << 4);

    f32x4 acc[4][2];
#pragma unroll
    for (int mt = 0; mt < 4; ++mt)
#pragma unroll
        for (int bt = 0; bt < 2; ++bt) acc[mt][bt] = (f32x4){0.f, 0.f, 0.f, 0.f};

    __syncthreads();

    for (int s = 0; s < 16; ++s) {
        const int buf = s & 1;
        if (s < 15) {
            async16(agp, &Al[buf ^ 1][w * 16 * 32]);
            async16(bgp, &Bl[buf ^ 1][w * 16 * 32]);
            agp += 32; bgp += 32;
        }
        const char* Ab = (const char*)&Al[buf][0];
        const char* Bb = (const char*)&Bl[buf][0];
        bf16x8 af[4], bfr[2];
#pragma unroll
        for (int mt = 0; mt < 4; ++mt)
            af[mt] = *(const bf16x8*)(Ab + wm * 4096 + mt * 1024 + FOFF);
#pragma unroll
        for (int bt = 0; bt < 2; ++bt)
            bfr[bt] = *(const bf16x8*)(Bb + wn * 2048 + bt * 1024 + FOFF);
#pragma unroll
        for (int mt = 0; mt < 4; ++mt)
#pragma unroll
            for (int bt = 0; bt < 2; ++bt)
                acc[mt][bt] = MFMA16(af[mt], bfr[bt], acc[mt][bt]);
        __syncthreads();
    }

    const int mat = my >> 2;                     // 0=Q, 1=K, 2=V
    const float* bias = (mat == 0) ? qb : (mat == 1) ? kb : vb;
    const int chbase = (my & 3) * 128 + wm * 64 + quad * 4;

    if (mat < 2) {
        u16* out = mat ? Kt : Qt;
        const float sc = mat ? 1.0f : 0.125f * LOG2E;
#pragma unroll
        for (int mt = 0; mt < 4; ++mt) {
            const int ch = chbase + mt * 16;
            float4 bv = *(const float4*)(bias + ch);
            float bvf[4] = {bv.x, bv.y, bv.z, bv.w};
#pragma unroll
            for (int bt = 0; bt < 2; ++bt) {
                int tok = n0 + wn * 32 + bt * 16 + lm;
                u16x4 pk;
#pragma unroll
                for (int r = 0; r < 4; ++r)
                    pk[r] = f2bf((acc[mt][bt][r] + bvf[r]) * sc);
                *(u16x4*)(out + (size_t)tok * 512 + ch) = pk;
            }
        }
    } else {
#pragma unroll
        for (int mt = 0; mt < 4; ++mt) {
            const int ch = chbase + mt * 16;
            float4 bv = *(const float4*)(bias + ch);
            float bvf[4] = {bv.x, bv.y, bv.z, bv.w};
#pragma unroll
            for (int bt = 0; bt < 2; ++bt) {
                int g = bt * 16 + lm;
                int col = n0 + wn * 32 + 8 * ((g >> 2) & 3) + 4 * ((g >> 4) & 1) + (g & 3);
#pragma unroll
                for (int r = 0; r < 4; ++r)
                    Vp[(size_t)(ch + r) * 4096 + col] = f2bf(acc[mt][bt][r] + bvf[r]);
            }
        }
    }
}

// ---------------------------------------------------------------------------
// Output projection, LDS-staged (unchanged, known-good).
// ---------------------------------------------------------------------------
__global__ __launch_bounds__(256, 2) void out_gemm(const u16* __restrict__ Wp,
                                                   const u16* __restrict__ Ot,
                                                   const float* __restrict__ pb,
                                                   float* __restrict__ out) {
    __shared__ __align__(16) u16 Al[2][128 * 32];
    __shared__ __align__(16) u16 Bl[2][64 * 32];

    const int tid = threadIdx.x;
    const int w = tid >> 6, lane = tid & 63;
    const int quad = lane >> 4, lm = lane & 15;
    const int wm = w & 1, wn = w >> 1;
    const int n0 = blockIdx.x * 64;
    const int m0 = blockIdx.y * 128;

    const int arow = lane >> 2;
    const int sch = (lane & 3) ^ ((lane >> 3) & 3);
    const u16* agp0 = Wp + (size_t)(m0 + w * 16 + arow) * 512 + sch * 8;
    const u16* agp1 = agp0 + (size_t)64 * 512;
    const u16* bgp = Ot + (size_t)(n0 + w * 16 + arow) * 512 + sch * 8;

    async16(agp0, &Al[0][w * 16 * 32]);
    async16(agp1, &Al[0][(64 + w * 16) * 32]);
    async16(bgp, &Bl[0][w * 16 * 32]);
    agp0 += 32; agp1 += 32; bgp += 32;

    const int FOFF = lm * 64 + ((quad ^ ((lm >> 1) & 3)) << 4);

    f32x4 acc[4][2];
#pragma unroll
    for (int mt = 0; mt < 4; ++mt)
#pragma unroll
        for (int bt = 0; bt < 2; ++bt) acc[mt][bt] = (f32x4){0.f, 0.f, 0.f, 0.f};

    __syncthreads();

    for (int s = 0; s < 16; ++s) {
        const int buf = s & 1;
        if (s < 15) {
            async16(agp0, &Al[buf ^ 1][w * 16 * 32]);
            async16(agp1, &Al[buf ^ 1][(64 + w * 16) * 32]);
            async16(bgp, &Bl[buf ^ 1][w * 16 * 32]);
            agp0 += 32; agp1 += 32; bgp += 32;
        }
        const char* Ab = (const char*)&Al[buf][0];
        const char* Bb = (const char*)&Bl[buf][0];
        bf16x8 af[4], bfr[2];
#pragma unroll
        for (int mt = 0; mt < 4; ++mt)
            af[mt] = *(const bf16x8*)(Ab + wm * 4096 + mt * 1024 + FOFF);
#pragma unroll
        for (int bt = 0; bt < 2; ++bt)
            bfr[bt] = *(const bf16x8*)(Bb + wn * 2048 + bt * 1024 + FOFF);
#pragma unroll
        for (int mt = 0; mt < 4; ++mt)
#pragma unroll
            for (int bt = 0; bt < 2; ++bt)
                acc[mt][bt] = MFMA16(af[mt], bfr[bt], acc[mt][bt]);
        __syncthreads();
    }

#pragma unroll
    for (int mt = 0; mt < 4; ++mt) {
        const int ch = m0 + wm * 64 + mt * 16 + quad * 4;
        float4 bv = *(const float4*)(pb + ch);
        float bvf[4] = {bv.x, bv.y, bv.z, bv.w};
#pragma unroll
        for (int bt = 0; bt < 2; ++bt) {
            int tok = n0 + wn * 32 + bt * 16 + lm;
#pragma unroll
            for (int r = 0; r < 4; ++r)
                out[(size_t)(ch + r) * 4096 + tok] = acc[mt][bt][r] + bvf[r];
        }
    }
}

// ---------------------------------------------------------------------------
// Flash attention, max-free softmax, split-K=4 — BARRIER-FREE main loop.
// R0/R1 post-mortem: ~1000 cyc/step stall from __syncthreads + vmcnt(0)
// drain; R2: direct-global loads = latency death. Fix: keep async LDS
// staging (proven layout from R1), make tiles WAVE-PRIVATE so no in-loop
// barrier exists; sync via counted inline-asm vmcnt (T3/T4).
// Block = 256 thr = 4 waves; wave w owns keys [w*1024, +1024) privately,
// all waves cover the same 64 queries (4 x 16q subtiles -> each ds_read
// feeds 4 MFMAs; 8 ds_read : 36 MFMA per 32-key step).
// LDS 64 KB: 4 waves x 2 bufs x (K 4KB | V 4KB). 2 blocks/CU.
// Prefetch distance 2 tiles; bias (lqw) register-prefetched 1 step ahead
// so its compiler wait is vmcnt(8), never a drain. vmcnt discipline:
// prologue [Q8, bias2, stage0 8, stage1 8]; body t: wait(10) = bias_t(2)+
// stage_{t+1}(8) newer than stage_t; t=0 waits 8, t=31 waits 2.
// Merge: split-K=4 add into dead staging LDS (swizzled slots), 2 barriers.
// ---------------------------------------------------------------------------
#define WAITVM(N) asm volatile("s_waitcnt vmcnt(" #N ")" ::: "memory")

__global__ __launch_bounds__(256, 2) void flash_attn(const u16* __restrict__ Qt,
                                                     const u16* __restrict__ Kt,
                                                     const u16* __restrict__ Vp,
                                                     const float* __restrict__ lqw2g,
                                                     u16* __restrict__ Ot) {
    __shared__ __align__(16) char smem[65536];

    const int tid = threadIdx.x;
    const int w = tid >> 6, lane = tid & 63;         // w = 0..3 (key quarter)
    const int quad = lane >> 4, lm = lane & 15;
    const int h = blockIdx.y, hq = h * 64;
    const int q0 = blockIdx.x * 64;
    const int kstart = w * 1024;

    char* kvw = smem + w * 16384;                    // private [buf][K 4KB|V 4KB]

    // staging lane addressing (XOR swizzle at global source, LDS linear)
    const int srow = lane >> 3;                      // 0..7
    const int schunk = (lane & 7) ^ srow;
    const u16* kg = Kt + (size_t)(kstart + srow) * 512 + hq + schunk * 8;
    const u16* vg = Vp + (size_t)(hq + 2 * srow + (schunk >> 2)) * 4096 +
                    kstart + (schunk & 3) * 8;

    // Q fragments: 4 subtiles x 2 d-halves (8 vmem loads)
    bf16x8 bq0[4], bq1[4];
#pragma unroll
    for (int s = 0; s < 4; ++s) {
        const u16* qb = Qt + (size_t)(q0 + s * 16 + lm) * 512 + hq + quad * 8;
        bq0[s] = ldg8(qb);
        bq1[s] = ldg8(qb + 32);
    }

    // bias prefetch registers (2 vmem loads)
    f32x4 breg0 = *(const f32x4*)(lqw2g + kstart + quad * 4);
    f32x4 breg1 = *(const f32x4*)(lqw2g + kstart + 16 + quad * 4);
    const float* bptr = lqw2g + kstart + 32 + quad * 4;

    // fragment read offsets (same proven layout as R1)
    const int A0 = lm * 128 + ((quad ^ (lm & 7)) << 4);       // K, d 0..31
    const int A1 = A0 ^ 64;                                   // K, d 32..63
    const int AV = (lm >> 1) * 128 +
                   (((4 * (lm & 1) + quad) ^ ((lm >> 1) & 7)) << 4);

#define STAGEBLK(DST)                                                          \
    {                                                                          \
        char* nb = (DST);                                                      \
        async16(kg, nb);                                                       \
        async16(kg + 8 * 512, nb + 1024);                                      \
        async16(kg + 16 * 512, nb + 2048);                                     \
        async16(kg + 24 * 512, nb + 3072);                                     \
        async16(vg, nb + 4096);                                                \
        async16(vg + (size_t)16 * 4096, nb + 5120);                            \
        async16(vg + (size_t)32 * 4096, nb + 6144);                            \
        async16(vg + (size_t)48 * 4096, nb + 7168);                            \
        kg += 32 * 512; vg += 32;                                              \
    }

    // stage tiles 0 and 1
    STAGEBLK(kvw)
    STAGEBLK(kvw + 8192)

    union { u32 u[4]; bf16x8 v; } onesu;
    onesu.u[0] = onesu.u[1] = onesu.u[2] = onesu.u[3] = 0x3F803F80u;
    const bf16x8 onesv = onesu.v;

    f32x4 acc_o[4][4];                                // [d-group][q-sub]
#pragma unroll
    for (int mt = 0; mt < 4; ++mt)
#pragma unroll
        for (int s = 0; s < 4; ++s) acc_o[mt][s] = (f32x4){0.f, 0.f, 0.f, 0.f};
    f32x4 acc_l[4];
#pragma unroll
    for (int s = 0; s < 4; ++s) acc_l[s] = (f32x4){0.f, 0.f, 0.f, 0.f};

    int bufsel = 0;

#define BODY(WN, DOBIAS, DOSTAGE)                                              \
    {                                                                          \
        WAITVM(WN);                                                            \
        const char* Kb = kvw + bufsel;                                         \
        const char* Vb = Kb + 4096;                                            \
        bf16x8 k00 = *(const bf16x8*)(Kb + A0);                                \
        bf16x8 k01 = *(const bf16x8*)(Kb + A1);                                \
        bf16x8 k10 = *(const bf16x8*)(Kb + 2048 + A0);                         \
        bf16x8 k11 = *(const bf16x8*)(Kb + 2048 + A1);                         \
        bf16x8 vf0 = *(const bf16x8*)(Vb + AV);                                \
        bf16x8 vf1 = *(const bf16x8*)(Vb + 1024 + AV);                         \
        bf16x8 vf2 = *(const bf16x8*)(Vb + 2048 + AV);                         \
        bf16x8 vf3 = *(const bf16x8*)(Vb + 3072 + AV);                         \
        u32 bbu[4][4];                                                         \
        _Pragma("unroll")                                                      \
        for (int s = 0; s < 4; ++s) {                                          \
            f32x4 a = MFMA16(k00, bq0[s], breg0);                              \
            a = MFMA16(k01, bq1[s], a);                                        \
            bbu[s][0] = pack2(EXP2F(a[0]), EXP2F(a[1]));                       \
            bbu[s][1] = pack2(EXP2F(a[2]), EXP2F(a[3]));                       \
        }                                                                      \
        _Pragma("unroll")                                                      \
        for (int s = 0; s < 4; ++s) {                                          \
            f32x4 a = MFMA16(k10, bq0[s], breg1);                              \
            a = MFMA16(k11, bq1[s], a);                                        \
            bbu[s][2] = pack2(EXP2F(a[0]), EXP2F(a[1]));                       \
            bbu[s][3] = pack2(EXP2F(a[2]), EXP2F(a[3]));                       \
        }                                                                      \
        if (DOBIAS) {                                                          \
            breg0 = *(const f32x4*)(bptr);                                     \
            breg1 = *(const f32x4*)(bptr + 16);                                \
            bptr += 32;                                                        \
        }                                                                      \
        union { u32 u[4]; bf16x8 v; } bb[4];                                   \
        _Pragma("unroll")                                                      \
        for (int s = 0; s < 4; ++s) {                                          \
            bb[s].u[0] = bbu[s][0]; bb[s].u[1] = bbu[s][1];                    \
            bb[s].u[2] = bbu[s][2]; bb[s].u[3] = bbu[s][3];                    \
        }                                                                      \
        _Pragma("unroll")                                                      \
        for (int s = 0; s < 4; ++s) {                                          \
            acc_o[0][s] = MFMA16(vf0, bb[s].v, acc_o[0][s]);                   \
            acc_o[1][s] = MFMA16(vf1, bb[s].v, acc_o[1][s]);                   \
            acc_o[2][s] = MFMA16(vf2, bb[s].v, acc_o[2][s]);                   \
            acc_o[3][s] = MFMA16(vf3, bb[s].v, acc_o[3][s]);                   \
            acc_l[s] = MFMA16(onesv, bb[s].v, acc_l[s]);                       \
        }                                                                      \
        if (DOSTAGE) STAGEBLK(kvw + bufsel)                                    \
        bufsel ^= 8192;                                                        \
    }

    BODY(8, true, true)                        // t = 0
    for (int t = 1; t < 30; ++t)
        BODY(10, true, true)                   // t = 1..29
    BODY(10, true, false)                      // t = 30 (bias_31, no stage)
    BODY(2, false, false)                      // t = 31

#undef BODY
#undef STAGEBLK

    // ---- split-K merge: pure add (max-free softmax), 4-way ----
    __syncthreads();                           // staging LDS now dead
    float* mbuf = (float*)smem;
    if (w != 0) {
        float* ob = mbuf + (w - 1) * 4096;     // 64 q x 64 d fp32
#pragma unroll
        for (int s = 0; s < 4; ++s) {
            const int r = s * 16 + lm;
#pragma unroll
            for (int mt = 0; mt < 4; ++mt) {
                const int sl = (mt * 4 + quad) ^ lm;
                *(f32x4*)(ob + r * 64 + sl * 4) = acc_o[mt][s];
            }
        }
        if (quad == 0) {
#pragma unroll
            for (int s = 0; s < 4; ++s)
                mbuf[12288 + (w - 1) * 64 + s * 16 + lm] = acc_l[s][0];
        }
    }
    __syncthreads();
    if (w != 0) return;

#pragma unroll
    for (int s = 0; s < 4; ++s) {
        const int r = s * 16 + lm;
        float lsum = acc_l[s][0];
#pragma unroll
        for (int p = 0; p < 3; ++p)
            lsum += mbuf[12288 + p * 64 + r];
        const float inv = 1.0f / lsum;
#pragma unroll
        for (int mt = 0; mt < 4; ++mt) {
            const int sl = (mt * 4 + quad) ^ lm;
            f32x4 o = acc_o[mt][s];
#pragma unroll
            for (int p = 0; p < 3; ++p)
                o += *(const f32x4*)(mbuf + p * 4096 + r * 64 + sl * 4);
            u16x4 pkv;
#pragma unroll
            for (int r2 = 0; r2 < 4; ++r2)
                pkv[r2] = f2bf(o[r2] * inv);
            *reinterpret_cast<u16x4*>(Ot + (size_t)(q0 + r) * 512 +
                                      hq + mt * 16 + quad * 4) = pkv;
        }
    }
}

// ---------------------------------------------------------------------------
extern "C" void kernel_launch(void* const* d_in, const int* in_sizes, int n_in,
                              void* d_out, int out_size, void* d_ws, size_t ws_size,
                              hipStream_t stream) {
    (void)in_sizes; (void)n_in; (void)out_size; (void)ws_size;
    const float* X   = (const float*)d_in[0];
    const float* qw  = (const float*)d_in[1];
    const float* qb  = (const float*)d_in[2];
    const float* kw  = (const float*)d_in[3];
    const float* kb  = (const float*)d_in[4];
    const float* vw  = (const float*)d_in[5];
    const float* vb  = (const float*)d_in[6];
    const float* pw  = (const float*)d_in[7];
    const float* pb  = (const float*)d_in[8];
    const float* lqw = (const float*)d_in[9];

    const size_t E = (size_t)4096 * 512;
    const size_t WE = (size_t)512 * 512;
    u16* Xt    = (u16*)d_ws;
    u16* Qt    = Xt + E;
    u16* Kt    = Qt + E;
    u16* Vp    = Kt + E;
    u16* Wqkv  = Vp + E;          // 1536 x 512 stacked
    u16* Wp    = Wqkv + 3 * WE;
    float* lqw2g = (float*)(Wp + WE);   // 4096 fp32, 16B-aligned
    u16* Ot    = Xt;              // reuse (dead after qkv)

    prep<<<dim3(64, 13), dim3(256), 0, stream>>>(X, Xt, qw, kw, vw, pw,
                                                 Wqkv, Wp, lqw, lqw2g);
    qkv_gemm<<<dim3(32, 12), dim3(512), 0, stream>>>(Wqkv, Xt, qb, kb, vb, Qt, Kt, Vp);
    flash_attn<<<dim3(64, 8), dim3(256), 0, stream>>>(Qt, Kt, Vp, lqw2g, Ot);
    out_gemm<<<dim3(64, 4), dim3(256), 0, stream>>>(Wp, Ot, pb, (float*)d_out);
}